// Round 3
// baseline (191.147 us; speedup 1.0000x reference)
//
#include <hip/hip_runtime.h>
#include <math.h>

// EKF propagate: B=65536 elements, nx=16, nz=8, nu=4, fp32.
// 16 lanes per element (lane t owns row t of all 16x16 matrices),
// 4 elements per wave, 16 per block. No __syncthreads: all cross-lane
// traffic is intra-wave via per-group LDS (in-order within one wave's
// instruction stream; __builtin_amdgcn_wave_barrier pins compiler order).
// Each group's LDS slice is touched by exactly one wave.
//
// R3 change vs R2 (84.5us, VALUBusy 53%, Occ 27%): K*S == tp exactly
// (K = tp*S^-1), so Joseph collapses to Sig_now = Sig_bar - K tp^T.
// Drops SB/KB buffers + K*S loop + half the final accumulation, and
// overlays TPT/SI/PIV/TPB into the dead VT region:
// GS 680 -> 424 floats => 27136 B/block => 6 blocks/CU (was 3).

namespace {

constexpr int GROUPS = 16;            // elements per block
constexpr int TPB    = GROUPS * 16;   // 256 threads

// Per-group LDS layout (floats). Overlays by liveness:
//  VT [0,320) lives only until the W-phase read; TPT/SI/PIV/TPB are all
//  written strictly after that read.
constexpr int O_VT  = 0;    // 16 rows x 20 (V transposed)   [phase V..W]
constexpr int O_TPT = 0;    // 8 rows x 20 (tp transposed)   [tp..S build]
constexpr int O_SI  = 160;  // 8 x 8  S^-1 rows              [GJ..K build]
constexpr int O_PIV = 224;  // 16 pivot row scratch           [GJ only]
constexpr int O_TPB = 240;  // 16 x 8 tp rows                [tp..final]
constexpr int O_VB  = 368;  // mubar[16] d[16] h[8] dh[8] = 48
constexpr int GS    = 424;  // GS % 32 == 8 -> the 4 groups of a wave sit at
                            // bank offsets {0,8,16,24}: broadcasts conflict-free
                            // GS % 4 == 0 -> float4 alignment preserved

__device__ __forceinline__ float dot4(float4 a, float4 b) {
  return a.x*b.x + a.y*b.y + a.z*b.z + a.w*b.w;
}

__global__ __launch_bounds__(TPB, 6)   // 6 blocks/CU target (VGPR cap 85)
void ekf_kernel(const float* __restrict__ mu_prev,
                const float* __restrict__ Sig_prev,
                const float* __restrict__ U,
                const float* __restrict__ Z,
                const float* __restrict__ A,
                const float* __restrict__ Bm,
                const float* __restrict__ C,
                const float* __restrict__ Q,
                const float* __restrict__ R,
                float* __restrict__ mu_out,
                float* __restrict__ sig_out,
                int Btot)
{
  __shared__ float lds[GS * GROUPS];   // 27136 B -> 6 blocks/CU (162816<=163840)
  const int tid = threadIdx.x;
  const int g = tid >> 4;
  const int t = tid & 15;
  int e = blockIdx.x * GROUPS + g;
  if (e >= Btot) e = Btot - 1;         // clamp; duplicate-write benign
  float* L = lds + g * GS;

  // ---- load Sigma row t (coalesced: wave covers a contiguous 4KB) ----
  float sig[16];
  {
    const float4* sp = (const float4*)(Sig_prev + (size_t)e * 256 + t * 16);
    #pragma unroll
    for (int c = 0; c < 4; c++) {
      float4 v = sp[c];
      sig[4*c+0] = v.x; sig[4*c+1] = v.y; sig[4*c+2] = v.z; sig[4*c+3] = v.w;
    }
  }

  // ---- mu_bar_t = tanh(A[t,:].mu + Bm[t,:].u), d_t = 1 - mu_bar^2 ----
  float pre;
  {
    const float4* ar = (const float4*)(A + t * 16);      // L1 row read
    const float4* mr = (const float4*)(mu_prev + (size_t)e * 16);
    pre = dot4(ar[0], mr[0]) + dot4(ar[1], mr[1])
        + dot4(ar[2], mr[2]) + dot4(ar[3], mr[3]);
    float4 b4 = *(const float4*)(Bm + t * 4);
    float4 u4 = *(const float4*)(U + (size_t)e * 4);
    pre += dot4(b4, u4);
  }
  const float mubar = tanhf(pre);
  const float dloc  = 1.0f - mubar * mubar;
  L[O_VB + t]      = mubar;
  L[O_VB + 16 + t] = dloc;
  __builtin_amdgcn_wave_barrier();

  // ---- h_bar, dh on lanes t<8 ----
  if (t < 8) {
    const float4* cr = (const float4*)(C + t * 16);
    const float4* mb = (const float4*)(L + O_VB);
    float ph = dot4(cr[0], mb[0]) + dot4(cr[1], mb[1])
             + dot4(cr[2], mb[2]) + dot4(cr[3], mb[3]);
    float hb = tanhf(ph);
    L[O_VB + 32 + t] = hb;
    L[O_VB + 40 + t] = 1.0f - hb * hb;
  }
  __builtin_amdgcn_wave_barrier();

  float dh[8];
  {
    float4 d0 = *(const float4*)(L + O_VB + 40);
    float4 d1 = *(const float4*)(L + O_VB + 44);
    dh[0]=d0.x; dh[1]=d0.y; dh[2]=d0.z; dh[3]=d0.w;
    dh[4]=d1.x; dh[5]=d1.y; dh[6]=d1.z; dh[7]=d1.w;
  }

  // ---- V = Sig * A^T (row t local; A rows via s_load), scatter V^T ----
  #pragma unroll
  for (int j = 0; j < 16; j++) {
    float acc = 0.f;
    #pragma unroll
    for (int k = 0; k < 16; k++) acc += sig[k] * A[j*16 + k];  // uniform -> s_load
    L[O_VT + j*20 + t] = acc;       // stride 20: 2-way max on scatter
  }
  __builtin_amdgcn_wave_barrier();

  // ---- W col t = A * V[:,t]  (== W row t, W symmetric) ----
  float sb[16];
  {
    float vcol[16];
    const float4* vt = (const float4*)(L + O_VT + t*20);
    #pragma unroll
    for (int c = 0; c < 4; c++) {
      float4 v = vt[c];
      vcol[4*c+0]=v.x; vcol[4*c+1]=v.y; vcol[4*c+2]=v.z; vcol[4*c+3]=v.w;
    }
    #pragma unroll
    for (int i = 0; i < 16; i++) {
      float acc = 0.f;
      #pragma unroll
      for (int k = 0; k < 16; k++) acc += A[i*16 + k] * vcol[k]; // s_load
      sb[i] = acc;
    }
  }
  __builtin_amdgcn_wave_barrier();   // VT dead from here; TPT/TPB may overlay

  // ---- Sig_bar row t = R[t,:] + d_t * W[t,:] * d ----
  {
    const float4* rr = (const float4*)(R + t * 16);
    const float4* dv = (const float4*)(L + O_VB + 16);
    #pragma unroll
    for (int c = 0; c < 4; c++) {
      float4 r4 = rr[c];
      float4 d4 = dv[c];
      sb[4*c+0] = r4.x + dloc * sb[4*c+0] * d4.x;
      sb[4*c+1] = r4.y + dloc * sb[4*c+1] * d4.y;
      sb[4*c+2] = r4.z + dloc * sb[4*c+2] * d4.z;
      sb[4*c+3] = r4.w + dloc * sb[4*c+3] * d4.w;
    }
  }

  // ---- tp row t = Sig_bar[t,:] C^T Dh ; stash transposed + row-major ----
  float tp[8];
  #pragma unroll
  for (int m = 0; m < 8; m++) {
    float acc = 0.f;
    #pragma unroll
    for (int k = 0; k < 16; k++) acc += sb[k] * C[m*16 + k];    // s_load
    tp[m] = acc * dh[m];
    L[O_TPT + m*20 + t] = tp[m];
  }
  *((float4*)(L + O_TPB + t*8 + 0)) = make_float4(tp[0], tp[1], tp[2], tp[3]);
  *((float4*)(L + O_TPB + t*8 + 4)) = make_float4(tp[4], tp[5], tp[6], tp[7]);
  __builtin_amdgcn_wave_barrier();

  // ---- S col t (== row t, S symmetric), Gauss-Jordan inverse (t<8) ----
  if (t < 8) {
    float tcol[16];
    const float4* tt = (const float4*)(L + O_TPT + t*20);
    #pragma unroll
    for (int c = 0; c < 4; c++) {
      float4 v = tt[c];
      tcol[4*c+0]=v.x; tcol[4*c+1]=v.y; tcol[4*c+2]=v.z; tcol[4*c+3]=v.w;
    }
    float s8[8];
    {
      float4 q0 = *(const float4*)(Q + t*8);       // Q row t == col t (sym)
      float4 q1 = *(const float4*)(Q + t*8 + 4);
      float qv[8] = {q0.x,q0.y,q0.z,q0.w,q1.x,q1.y,q1.z,q1.w};
      #pragma unroll
      for (int m = 0; m < 8; m++) {
        float acc = 0.f;
        #pragma unroll
        for (int k = 0; k < 16; k++) acc += C[m*16 + k] * tcol[k]; // s_load
        s8[m] = acc * dh[m] + qv[m];
      }
    }

    // Gauss-Jordan (S is SPD -> no pivoting); rows live in registers.
    float x8[8];
    #pragma unroll
    for (int j = 0; j < 8; j++) x8[j] = (j == t) ? 1.0f : 0.0f;
    #pragma unroll
    for (int p = 0; p < 8; p++) {
      if (t == p) {
        float rcp = 1.0f / s8[p];   // IEEE div (no fast-math)
        #pragma unroll
        for (int j = 0; j < 8; j++) { s8[j] *= rcp; x8[j] *= rcp; }
        *((float4*)(L + O_PIV + 0))  = make_float4(s8[0], s8[1], s8[2], s8[3]);
        *((float4*)(L + O_PIV + 4))  = make_float4(s8[4], s8[5], s8[6], s8[7]);
        *((float4*)(L + O_PIV + 8))  = make_float4(x8[0], x8[1], x8[2], x8[3]);
        *((float4*)(L + O_PIV + 12)) = make_float4(x8[4], x8[5], x8[6], x8[7]);
      }
      __builtin_amdgcn_wave_barrier();
      if (t != p) {
        float f = s8[p];
        float4 pa = *(const float4*)(L + O_PIV + 0);
        float4 pb = *(const float4*)(L + O_PIV + 4);
        float4 pc = *(const float4*)(L + O_PIV + 8);
        float4 pd = *(const float4*)(L + O_PIV + 12);
        s8[0]-=f*pa.x; s8[1]-=f*pa.y; s8[2]-=f*pa.z; s8[3]-=f*pa.w;
        s8[4]-=f*pb.x; s8[5]-=f*pb.y; s8[6]-=f*pb.z; s8[7]-=f*pb.w;
        x8[0]-=f*pc.x; x8[1]-=f*pc.y; x8[2]-=f*pc.z; x8[3]-=f*pc.w;
        x8[4]-=f*pd.x; x8[5]-=f*pd.y; x8[6]-=f*pd.z; x8[7]-=f*pd.w;
      }
      __builtin_amdgcn_wave_barrier();
    }
    *((float4*)(L + O_SI + t*8 + 0)) = make_float4(x8[0], x8[1], x8[2], x8[3]);
    *((float4*)(L + O_SI + t*8 + 4)) = make_float4(x8[4], x8[5], x8[6], x8[7]);
  }
  __builtin_amdgcn_wave_barrier();

  // ---- K row t = tp[t,:] @ Sinv ----
  float kreg[8] = {0,0,0,0,0,0,0,0};
  #pragma unroll
  for (int m = 0; m < 8; m++) {
    float tpm = tp[m];
    float4 a = *(const float4*)(L + O_SI + m*8 + 0);
    float4 b = *(const float4*)(L + O_SI + m*8 + 4);
    kreg[0]+=tpm*a.x; kreg[1]+=tpm*a.y; kreg[2]+=tpm*a.z; kreg[3]+=tpm*a.w;
    kreg[4]+=tpm*b.x; kreg[5]+=tpm*b.y; kreg[6]+=tpm*b.z; kreg[7]+=tpm*b.w;
  }

  // ---- mu_now_t = mu_bar_t + K[t,:].(z - h_bar) ----
  {
    float4 z0 = *(const float4*)(Z + (size_t)e * 8);
    float4 z1 = *(const float4*)(Z + (size_t)e * 8 + 4);
    float4 h0 = *(const float4*)(L + O_VB + 32);
    float4 h1 = *(const float4*)(L + O_VB + 36);
    float mu_now = mubar
      + kreg[0]*(z0.x-h0.x) + kreg[1]*(z0.y-h0.y)
      + kreg[2]*(z0.z-h0.z) + kreg[3]*(z0.w-h0.w)
      + kreg[4]*(z1.x-h1.x) + kreg[5]*(z1.y-h1.y)
      + kreg[6]*(z1.z-h1.z) + kreg[7]*(z1.w-h1.w);
    mu_out[(size_t)e * 16 + t] = mu_now;
  }

  // ---- Sig_now = Sig_bar - K tp^T  (== Joseph form exactly in real
  //      arithmetic, since K S = tp S^-1 S = tp; fp delta ~1e-6) ----
  float out[16];
  #pragma unroll
  for (int i = 0; i < 16; i++) {
    float4 ta = *(const float4*)(L + O_TPB + i*8 + 0);
    float4 tb = *(const float4*)(L + O_TPB + i*8 + 4);
    float acc = sb[i];
    acc -= kreg[0]*ta.x + kreg[1]*ta.y + kreg[2]*ta.z + kreg[3]*ta.w
         + kreg[4]*tb.x + kreg[5]*tb.y + kreg[6]*tb.z + kreg[7]*tb.w;
    out[i] = acc;
  }
  {
    float4* op = (float4*)(sig_out + (size_t)e * 256 + t * 16);
    op[0] = make_float4(out[0],  out[1],  out[2],  out[3]);
    op[1] = make_float4(out[4],  out[5],  out[6],  out[7]);
    op[2] = make_float4(out[8],  out[9],  out[10], out[11]);
    op[3] = make_float4(out[12], out[13], out[14], out[15]);
  }
}

} // namespace

extern "C" void kernel_launch(void* const* d_in, const int* in_sizes, int n_in,
                              void* d_out, int out_size, void* d_ws, size_t ws_size,
                              hipStream_t stream)
{
  const float* mu_prev = (const float*)d_in[0];
  const float* Sigma   = (const float*)d_in[1];
  const float* u       = (const float*)d_in[2];
  const float* z       = (const float*)d_in[3];
  const float* A       = (const float*)d_in[4];
  const float* Bm      = (const float*)d_in[5];
  const float* C       = (const float*)d_in[6];
  const float* Q       = (const float*)d_in[7];
  const float* R       = (const float*)d_in[8];

  const int Btot = in_sizes[0] / 16;                 // B = 65536
  float* mu_out  = (float*)d_out;
  float* sig_out = (float*)d_out + (size_t)Btot * 16;

  const int grid = (Btot + GROUPS - 1) / GROUPS;     // 4096 blocks x 256 thr
  ekf_kernel<<<grid, TPB, 0, stream>>>(mu_prev, Sigma, u, z, A, Bm, C, Q, R,
                                       mu_out, sig_out, Btot);
}

// Round 4
// 162.779 us; speedup vs baseline: 1.1743x; 1.1743x over previous
//
#include <hip/hip_runtime.h>
#include <math.h>

// EKF propagate: B=65536 elements, nx=16, nz=8, nu=4, fp32.
// 16 lanes per element (lane t owns row t of all 16x16 matrices),
// 4 elements per wave, 16 per block. No __syncthreads: all cross-lane
// traffic is intra-wave via per-group LDS (in-order within one wave's
// instruction stream; __builtin_amdgcn_wave_barrier pins compiler order).
// Each group's LDS slice is touched by exactly one wave.
//
// R4 change vs R3 (90.7us): drop the min-waves clause from
// __launch_bounds__. R3's (256,6) forced VGPR 68->40 via scratch spills
// (+97MB WRITE, +45MB FETCH -> net regression). LDS (27136B -> 6
// blocks/CU) is the intended occupancy limiter; the natural ~60-70 VGPR
// allocation supports that without any cap.

namespace {

constexpr int GROUPS = 16;            // elements per block
constexpr int TPB    = GROUPS * 16;   // 256 threads

// Per-group LDS layout (floats). Overlays by liveness:
//  VT [0,320) lives only until the W-phase read; TPT/SI/PIV/TPB are all
//  written strictly after that read.
constexpr int O_VT  = 0;    // 16 rows x 20 (V transposed)   [phase V..W]
constexpr int O_TPT = 0;    // 8 rows x 20 (tp transposed)   [tp..S build]
constexpr int O_SI  = 160;  // 8 x 8  S^-1 rows              [GJ..K build]
constexpr int O_PIV = 224;  // 16 pivot row scratch           [GJ only]
constexpr int O_TPB = 240;  // 16 x 8 tp rows                [tp..final]
constexpr int O_VB  = 368;  // mubar[16] d[16] h[8] dh[8] = 48
constexpr int GS    = 424;  // GS % 32 == 8 -> the 4 groups of a wave sit at
                            // bank offsets {0,8,16,24}: broadcasts conflict-free
                            // GS % 4 == 0 -> float4 alignment preserved

__device__ __forceinline__ float dot4(float4 a, float4 b) {
  return a.x*b.x + a.y*b.y + a.z*b.z + a.w*b.w;
}

__global__ __launch_bounds__(TPB)     // NO min-waves: R3's (TPB,6) spilled
void ekf_kernel(const float* __restrict__ mu_prev,
                const float* __restrict__ Sig_prev,
                const float* __restrict__ U,
                const float* __restrict__ Z,
                const float* __restrict__ A,
                const float* __restrict__ Bm,
                const float* __restrict__ C,
                const float* __restrict__ Q,
                const float* __restrict__ R,
                float* __restrict__ mu_out,
                float* __restrict__ sig_out,
                int Btot)
{
  __shared__ float lds[GS * GROUPS];   // 27136 B -> 6 blocks/CU (162816<=163840)
  const int tid = threadIdx.x;
  const int g = tid >> 4;
  const int t = tid & 15;
  int e = blockIdx.x * GROUPS + g;
  if (e >= Btot) e = Btot - 1;         // clamp; duplicate-write benign
  float* L = lds + g * GS;

  // ---- load Sigma row t (coalesced: wave covers a contiguous 4KB) ----
  float sig[16];
  {
    const float4* sp = (const float4*)(Sig_prev + (size_t)e * 256 + t * 16);
    #pragma unroll
    for (int c = 0; c < 4; c++) {
      float4 v = sp[c];
      sig[4*c+0] = v.x; sig[4*c+1] = v.y; sig[4*c+2] = v.z; sig[4*c+3] = v.w;
    }
  }

  // ---- mu_bar_t = tanh(A[t,:].mu + Bm[t,:].u), d_t = 1 - mu_bar^2 ----
  float pre;
  {
    const float4* ar = (const float4*)(A + t * 16);      // L1 row read
    const float4* mr = (const float4*)(mu_prev + (size_t)e * 16);
    pre = dot4(ar[0], mr[0]) + dot4(ar[1], mr[1])
        + dot4(ar[2], mr[2]) + dot4(ar[3], mr[3]);
    float4 b4 = *(const float4*)(Bm + t * 4);
    float4 u4 = *(const float4*)(U + (size_t)e * 4);
    pre += dot4(b4, u4);
  }
  const float mubar = tanhf(pre);
  const float dloc  = 1.0f - mubar * mubar;
  L[O_VB + t]      = mubar;
  L[O_VB + 16 + t] = dloc;
  __builtin_amdgcn_wave_barrier();

  // ---- h_bar, dh on lanes t<8 ----
  if (t < 8) {
    const float4* cr = (const float4*)(C + t * 16);
    const float4* mb = (const float4*)(L + O_VB);
    float ph = dot4(cr[0], mb[0]) + dot4(cr[1], mb[1])
             + dot4(cr[2], mb[2]) + dot4(cr[3], mb[3]);
    float hb = tanhf(ph);
    L[O_VB + 32 + t] = hb;
    L[O_VB + 40 + t] = 1.0f - hb * hb;
  }
  __builtin_amdgcn_wave_barrier();

  float dh[8];
  {
    float4 d0 = *(const float4*)(L + O_VB + 40);
    float4 d1 = *(const float4*)(L + O_VB + 44);
    dh[0]=d0.x; dh[1]=d0.y; dh[2]=d0.z; dh[3]=d0.w;
    dh[4]=d1.x; dh[5]=d1.y; dh[6]=d1.z; dh[7]=d1.w;
  }

  // ---- V = Sig * A^T (row t local; A rows via s_load), scatter V^T ----
  #pragma unroll
  for (int j = 0; j < 16; j++) {
    float acc = 0.f;
    #pragma unroll
    for (int k = 0; k < 16; k++) acc += sig[k] * A[j*16 + k];  // uniform -> s_load
    L[O_VT + j*20 + t] = acc;       // stride 20: 2-way max on scatter
  }
  __builtin_amdgcn_wave_barrier();

  // ---- W col t = A * V[:,t]  (== W row t, W symmetric) ----
  float sb[16];
  {
    float vcol[16];
    const float4* vt = (const float4*)(L + O_VT + t*20);
    #pragma unroll
    for (int c = 0; c < 4; c++) {
      float4 v = vt[c];
      vcol[4*c+0]=v.x; vcol[4*c+1]=v.y; vcol[4*c+2]=v.z; vcol[4*c+3]=v.w;
    }
    #pragma unroll
    for (int i = 0; i < 16; i++) {
      float acc = 0.f;
      #pragma unroll
      for (int k = 0; k < 16; k++) acc += A[i*16 + k] * vcol[k]; // s_load
      sb[i] = acc;
    }
  }
  __builtin_amdgcn_wave_barrier();   // VT dead from here; TPT/TPB may overlay

  // ---- Sig_bar row t = R[t,:] + d_t * W[t,:] * d ----
  {
    const float4* rr = (const float4*)(R + t * 16);
    const float4* dv = (const float4*)(L + O_VB + 16);
    #pragma unroll
    for (int c = 0; c < 4; c++) {
      float4 r4 = rr[c];
      float4 d4 = dv[c];
      sb[4*c+0] = r4.x + dloc * sb[4*c+0] * d4.x;
      sb[4*c+1] = r4.y + dloc * sb[4*c+1] * d4.y;
      sb[4*c+2] = r4.z + dloc * sb[4*c+2] * d4.z;
      sb[4*c+3] = r4.w + dloc * sb[4*c+3] * d4.w;
    }
  }

  // ---- tp row t = Sig_bar[t,:] C^T Dh ; stash transposed + row-major ----
  float tp[8];
  #pragma unroll
  for (int m = 0; m < 8; m++) {
    float acc = 0.f;
    #pragma unroll
    for (int k = 0; k < 16; k++) acc += sb[k] * C[m*16 + k];    // s_load
    tp[m] = acc * dh[m];
    L[O_TPT + m*20 + t] = tp[m];
  }
  *((float4*)(L + O_TPB + t*8 + 0)) = make_float4(tp[0], tp[1], tp[2], tp[3]);
  *((float4*)(L + O_TPB + t*8 + 4)) = make_float4(tp[4], tp[5], tp[6], tp[7]);
  __builtin_amdgcn_wave_barrier();

  // ---- S col t (== row t, S symmetric), Gauss-Jordan inverse (t<8) ----
  if (t < 8) {
    float tcol[16];
    const float4* tt = (const float4*)(L + O_TPT + t*20);
    #pragma unroll
    for (int c = 0; c < 4; c++) {
      float4 v = tt[c];
      tcol[4*c+0]=v.x; tcol[4*c+1]=v.y; tcol[4*c+2]=v.z; tcol[4*c+3]=v.w;
    }
    float s8[8];
    {
      float4 q0 = *(const float4*)(Q + t*8);       // Q row t == col t (sym)
      float4 q1 = *(const float4*)(Q + t*8 + 4);
      float qv[8] = {q0.x,q0.y,q0.z,q0.w,q1.x,q1.y,q1.z,q1.w};
      #pragma unroll
      for (int m = 0; m < 8; m++) {
        float acc = 0.f;
        #pragma unroll
        for (int k = 0; k < 16; k++) acc += C[m*16 + k] * tcol[k]; // s_load
        s8[m] = acc * dh[m] + qv[m];
      }
    }

    // Gauss-Jordan (S is SPD -> no pivoting); rows live in registers.
    float x8[8];
    #pragma unroll
    for (int j = 0; j < 8; j++) x8[j] = (j == t) ? 1.0f : 0.0f;
    #pragma unroll
    for (int p = 0; p < 8; p++) {
      if (t == p) {
        float rcp = 1.0f / s8[p];   // IEEE div (no fast-math)
        #pragma unroll
        for (int j = 0; j < 8; j++) { s8[j] *= rcp; x8[j] *= rcp; }
        *((float4*)(L + O_PIV + 0))  = make_float4(s8[0], s8[1], s8[2], s8[3]);
        *((float4*)(L + O_PIV + 4))  = make_float4(s8[4], s8[5], s8[6], s8[7]);
        *((float4*)(L + O_PIV + 8))  = make_float4(x8[0], x8[1], x8[2], x8[3]);
        *((float4*)(L + O_PIV + 12)) = make_float4(x8[4], x8[5], x8[6], x8[7]);
      }
      __builtin_amdgcn_wave_barrier();
      if (t != p) {
        float f = s8[p];
        float4 pa = *(const float4*)(L + O_PIV + 0);
        float4 pb = *(const float4*)(L + O_PIV + 4);
        float4 pc = *(const float4*)(L + O_PIV + 8);
        float4 pd = *(const float4*)(L + O_PIV + 12);
        s8[0]-=f*pa.x; s8[1]-=f*pa.y; s8[2]-=f*pa.z; s8[3]-=f*pa.w;
        s8[4]-=f*pb.x; s8[5]-=f*pb.y; s8[6]-=f*pb.z; s8[7]-=f*pb.w;
        x8[0]-=f*pc.x; x8[1]-=f*pc.y; x8[2]-=f*pc.z; x8[3]-=f*pc.w;
        x8[4]-=f*pd.x; x8[5]-=f*pd.y; x8[6]-=f*pd.z; x8[7]-=f*pd.w;
      }
      __builtin_amdgcn_wave_barrier();
    }
    *((float4*)(L + O_SI + t*8 + 0)) = make_float4(x8[0], x8[1], x8[2], x8[3]);
    *((float4*)(L + O_SI + t*8 + 4)) = make_float4(x8[4], x8[5], x8[6], x8[7]);
  }
  __builtin_amdgcn_wave_barrier();

  // ---- K row t = tp[t,:] @ Sinv ----
  float kreg[8] = {0,0,0,0,0,0,0,0};
  #pragma unroll
  for (int m = 0; m < 8; m++) {
    float tpm = tp[m];
    float4 a = *(const float4*)(L + O_SI + m*8 + 0);
    float4 b = *(const float4*)(L + O_SI + m*8 + 4);
    kreg[0]+=tpm*a.x; kreg[1]+=tpm*a.y; kreg[2]+=tpm*a.z; kreg[3]+=tpm*a.w;
    kreg[4]+=tpm*b.x; kreg[5]+=tpm*b.y; kreg[6]+=tpm*b.z; kreg[7]+=tpm*b.w;
  }

  // ---- mu_now_t = mu_bar_t + K[t,:].(z - h_bar) ----
  {
    float4 z0 = *(const float4*)(Z + (size_t)e * 8);
    float4 z1 = *(const float4*)(Z + (size_t)e * 8 + 4);
    float4 h0 = *(const float4*)(L + O_VB + 32);
    float4 h1 = *(const float4*)(L + O_VB + 36);
    float mu_now = mubar
      + kreg[0]*(z0.x-h0.x) + kreg[1]*(z0.y-h0.y)
      + kreg[2]*(z0.z-h0.z) + kreg[3]*(z0.w-h0.w)
      + kreg[4]*(z1.x-h1.x) + kreg[5]*(z1.y-h1.y)
      + kreg[6]*(z1.z-h1.z) + kreg[7]*(z1.w-h1.w);
    mu_out[(size_t)e * 16 + t] = mu_now;
  }

  // ---- Sig_now = Sig_bar - K tp^T  (== Joseph form exactly in real
  //      arithmetic, since K S = tp S^-1 S = tp; fp delta ~1e-6) ----
  float out[16];
  #pragma unroll
  for (int i = 0; i < 16; i++) {
    float4 ta = *(const float4*)(L + O_TPB + i*8 + 0);
    float4 tb = *(const float4*)(L + O_TPB + i*8 + 4);
    float acc = sb[i];
    acc -= kreg[0]*ta.x + kreg[1]*ta.y + kreg[2]*ta.z + kreg[3]*ta.w
         + kreg[4]*tb.x + kreg[5]*tb.y + kreg[6]*tb.z + kreg[7]*tb.w;
    out[i] = acc;
  }
  {
    float4* op = (float4*)(sig_out + (size_t)e * 256 + t * 16);
    op[0] = make_float4(out[0],  out[1],  out[2],  out[3]);
    op[1] = make_float4(out[4],  out[5],  out[6],  out[7]);
    op[2] = make_float4(out[8],  out[9],  out[10], out[11]);
    op[3] = make_float4(out[12], out[13], out[14], out[15]);
  }
}

} // namespace

extern "C" void kernel_launch(void* const* d_in, const int* in_sizes, int n_in,
                              void* d_out, int out_size, void* d_ws, size_t ws_size,
                              hipStream_t stream)
{
  const float* mu_prev = (const float*)d_in[0];
  const float* Sigma   = (const float*)d_in[1];
  const float* u       = (const float*)d_in[2];
  const float* z       = (const float*)d_in[3];
  const float* A       = (const float*)d_in[4];
  const float* Bm      = (const float*)d_in[5];
  const float* C       = (const float*)d_in[6];
  const float* Q       = (const float*)d_in[7];
  const float* R       = (const float*)d_in[8];

  const int Btot = in_sizes[0] / 16;                 // B = 65536
  float* mu_out  = (float*)d_out;
  float* sig_out = (float*)d_out + (size_t)Btot * 16;

  const int grid = (Btot + GROUPS - 1) / GROUPS;     // 4096 blocks x 256 thr
  ekf_kernel<<<grid, TPB, 0, stream>>>(mu_prev, Sigma, u, z, A, Bm, C, Q, R,
                                       mu_out, sig_out, Btot);
}